// Round 1
// baseline (715.599 us; speedup 1.0000x reference)
//
#include <hip/hip_runtime.h>
#include <cstdint>

typedef unsigned short u16;
typedef unsigned int u32;
typedef __bf16 bf16x8 __attribute__((ext_vector_type(8)));
typedef float f32x4 __attribute__((ext_vector_type(4)));
typedef u16 u16x8 __attribute__((ext_vector_type(8)));

#define GLOBAL_AS __attribute__((address_space(1)))
#define LDS_AS __attribute__((address_space(3)))

// fp32 -> bf16 (RNE)
__device__ __forceinline__ u16 f2b(float f) {
  u32 u = __builtin_bit_cast(u32, f);
  u += 0x7fffu + ((u >> 16) & 1u);
  return (u16)(u >> 16);
}

// ---------------------------------------------------------------------------
// Tiled transpose + fp32->bf16 convert: out[n*K + k] = bf16(in[k*N + n])
// block (32,8), grid (N/32, K/32)
// ---------------------------------------------------------------------------
__global__ void transpose_cvt(const float* __restrict__ in, u16* __restrict__ out,
                              int K, int N) {
  __shared__ float tile[32][33];
  const int tx = threadIdx.x, ty = threadIdx.y;
  const int n0 = blockIdx.x * 32, k0 = blockIdx.y * 32;
#pragma unroll
  for (int i = 0; i < 4; i++)
    tile[ty + i * 8][tx] = in[(size_t)(k0 + ty + i * 8) * N + n0 + tx];
  __syncthreads();
#pragma unroll
  for (int i = 0; i < 4; i++)
    out[(size_t)(n0 + ty + i * 8) * K + k0 + tx] = f2b(tile[tx][ty + i * 8]);
}

// ---------------------------------------------------------------------------
// LayerNorm: one wave per row of 1024 fp32, bf16 out. block 256 = 4 rows.
// ---------------------------------------------------------------------------
__global__ __launch_bounds__(256) void ln_fwd(const float* __restrict__ x,
                                              const float* __restrict__ gamma,
                                              const float* __restrict__ beta,
                                              u16* __restrict__ out) {
  const int wid = threadIdx.x >> 6, lane = threadIdx.x & 63;
  const size_t row = (size_t)blockIdx.x * 4 + wid;
  const float* xr = x + row * 1024;
  float4 v[4];
  float s = 0.f, s2 = 0.f;
#pragma unroll
  for (int i = 0; i < 4; i++) {
    v[i] = *(const float4*)(xr + i * 256 + lane * 4);
    s += v[i].x + v[i].y + v[i].z + v[i].w;
    s2 += v[i].x * v[i].x + v[i].y * v[i].y + v[i].z * v[i].z + v[i].w * v[i].w;
  }
#pragma unroll
  for (int m = 1; m < 64; m <<= 1) {
    s += __shfl_xor(s, m);
    s2 += __shfl_xor(s2, m);
  }
  const float mu = s * (1.f / 1024.f);
  const float var = s2 * (1.f / 1024.f) - mu * mu;
  const float rs = rsqrtf(var + 1e-5f);
  u16* orow = out + row * 1024;
#pragma unroll
  for (int i = 0; i < 4; i++) {
    float4 gv = *(const float4*)(gamma + i * 256 + lane * 4);
    float4 bv = *(const float4*)(beta + i * 256 + lane * 4);
    float y0 = (v[i].x - mu) * rs * gv.x + bv.x;
    float y1 = (v[i].y - mu) * rs * gv.y + bv.y;
    float y2 = (v[i].z - mu) * rs * gv.z + bv.z;
    float y3 = (v[i].w - mu) * rs * gv.w + bv.w;
    uint2 pk;
    pk.x = (u32)f2b(y0) | ((u32)f2b(y1) << 16);
    pk.y = (u32)f2b(y2) | ((u32)f2b(y3) << 16);
    *(uint2*)(orow + i * 256 + lane * 4) = pk;
  }
}

// ---------------------------------------------------------------------------
// GEMM C[M,N] = A[M,K] (bf16, row-major) * BT[N,K] (bf16, row-major) + epilogue
// m97 structure: 128x128 tile, BK=64, 4 waves (2x2), 16x16x32 MFMA,
// global_load_lds width 16, 2-barrier K loop.
// MODE 0: QKV  -> bf16 out = (acc + bias_sel[col]) * (qcols ? 0.125*log2e : 1)
// MODE 1: FFN1 -> bf16 out = relu(acc + b0[col])
// MODE 2: RES  -> f32 out  = acc + b0[col] + res[row,col]
// ---------------------------------------------------------------------------
template <int MODE>
__global__ __launch_bounds__(256) void gemm_bt(
    const u16* __restrict__ A, const u16* __restrict__ BT,
    const float* __restrict__ b0, const float* __restrict__ b1,
    const float* __restrict__ b2, const float* __restrict__ res,
    void* __restrict__ outp, int M, int N, int K) {
  __shared__ __align__(16) u16 Alds[128 * 64];
  __shared__ __align__(16) u16 Blds[128 * 64];
  const int tid = threadIdx.x;
  const int wid = tid >> 6, lane = tid & 63;
  const int wm = wid >> 1, wn = wid & 1;
  const int g = lane >> 4, l15 = lane & 15;
  const int bm = blockIdx.y * 128, bn = blockIdx.x * 128;

  f32x4 acc[4][4] = {};

  const int srow = wid * 32 + (lane >> 3);
  const int scol = (lane & 7) * 8;
  const u16* Ag = A + (size_t)(bm + srow) * K + scol;
  const u16* Bg = BT + (size_t)(bn + srow) * K + scol;

  for (int k0 = 0; k0 < K; k0 += 64) {
    __syncthreads();
#pragma unroll
    for (int i = 0; i < 4; i++)
      __builtin_amdgcn_global_load_lds(
          (const GLOBAL_AS u32*)(Ag + (size_t)(i * 8) * K + k0),
          (LDS_AS u32*)&Alds[(wid * 32 + i * 8) * 64], 16, 0, 0);
#pragma unroll
    for (int i = 0; i < 4; i++)
      __builtin_amdgcn_global_load_lds(
          (const GLOBAL_AS u32*)(Bg + (size_t)(i * 8) * K + k0),
          (LDS_AS u32*)&Blds[(wid * 32 + i * 8) * 64], 16, 0, 0);
    __syncthreads();
#pragma unroll
    for (int ks = 0; ks < 2; ks++) {
      bf16x8 af[4], bfr[4];
#pragma unroll
      for (int mt = 0; mt < 4; mt++)
        af[mt] = *(const bf16x8*)&Alds[(wm * 64 + mt * 16 + l15) * 64 + ks * 32 + g * 8];
#pragma unroll
      for (int nt = 0; nt < 4; nt++)
        bfr[nt] = *(const bf16x8*)&Blds[(wn * 64 + nt * 16 + l15) * 64 + ks * 32 + g * 8];
#pragma unroll
      for (int mt = 0; mt < 4; mt++)
#pragma unroll
        for (int nt = 0; nt < 4; nt++)
          acc[mt][nt] = __builtin_amdgcn_mfma_f32_16x16x32_bf16(
              af[mt], bfr[nt], acc[mt][nt], 0, 0, 0);
    }
  }

  // epilogue
  const float* bias = b0;
  float scale = 1.f;
  if (MODE == 0) {
    bias = (bn < 1024) ? b0 : (bn < 2048 ? b1 : b2);
    if (bn < 1024) scale = 0.18033688011112042f;  // 0.125 * log2(e)
  }
#pragma unroll
  for (int mt = 0; mt < 4; mt++) {
#pragma unroll
    for (int nt = 0; nt < 4; nt++) {
      const int orow = bm + wm * 64 + mt * 16 + g * 4;
      const int ocol = bn + wn * 64 + nt * 16 + l15;
      const float bv = bias[MODE == 0 ? (ocol & 1023) : ocol];
#pragma unroll
      for (int r = 0; r < 4; r++) {
        const float v = acc[mt][nt][r] + bv;
        const size_t oi = (size_t)(orow + r) * N + ocol;
        if (MODE == 0)
          ((u16*)outp)[oi] = f2b(v * scale);
        else if (MODE == 1)
          ((u16*)outp)[oi] = f2b(v > 0.f ? v : 0.f);
        else
          ((float*)outp)[oi] = v + res[oi];
      }
    }
  }
}

// ---------------------------------------------------------------------------
// Flash attention fwd. QKV [8192][3072] bf16 (Q | K | V blocks of 1024 cols,
// head h = 64 cols). Q pre-scaled by 0.125*log2e, so P = exp2(S - m).
// Block = (qt, h, b): 64 q-rows, 4 waves x 16 q-rows. KV tile = 64.
// K and V^T staged in LDS with XOR swizzle on the 8-elem group index.
// ---------------------------------------------------------------------------
__global__ __launch_bounds__(256) void attn_fwd(const u16* __restrict__ QKV,
                                                u16* __restrict__ ctx) {
  __shared__ __align__(16) u16 Klds[64 * 64];
  __shared__ __align__(16) u16 Vt[64 * 64];
  __shared__ __align__(16) u16 Plds[4][16 * 64];
  const int tid = threadIdx.x;
  const int wid = tid >> 6, lane = tid & 63;
  const int g = lane >> 4, l15 = lane & 15, l7 = lane & 7;
  const int qt = blockIdx.x, h = blockIdx.y, b = blockIdx.z;

  // Q fragments (A-operand): lane holds row l15, k = ks*32 + g*8 + j
  const u16* Qbase = QKV + (size_t)(b * 2048 + qt * 64 + wid * 16) * 3072 + h * 64;
  bf16x8 qf[2];
#pragma unroll
  for (int ks = 0; ks < 2; ks++)
    qf[ks] = *(const bf16x8*)(Qbase + (size_t)l15 * 3072 + ks * 32 + g * 8);

  const u16* Kg = QKV + (size_t)(b * 2048) * 3072 + 1024 + h * 64;
  const u16* Vg = QKV + (size_t)(b * 2048) * 3072 + 2048 + h * 64;

  float mrun[4], lrun[4];
  f32x4 cacc[4] = {};
#pragma unroll
  for (int r = 0; r < 4; r++) {
    mrun[r] = -3.0e38f;
    lrun[r] = 0.f;
  }

  const int skv0 = (tid & 31) * 2, sd0 = (tid >> 5) * 8;

  for (int t = 0; t < 32; t++) {
    __syncthreads();  // previous tile's LDS reads complete
    // ---- stage K [kv][d], swizzled: dgrp ^= (kv&7)
#pragma unroll
    for (int i = 0; i < 2; i++) {
      const int c = tid + 256 * i;
      const int kv = c >> 3, dg = c & 7;
      u16x8 kval = *(const u16x8*)(Kg + (size_t)(t * 64 + kv) * 3072 + dg * 8);
      *(u16x8*)&Klds[kv * 64 + ((dg ^ (kv & 7)) << 3)] = kval;
    }
    // ---- stage V transposed Vt[d][kv], swizzled: kvgrp ^= (d&7); pack 2 kv per u32
    {
      u16x8 v0 = *(const u16x8*)(Vg + (size_t)(t * 64 + skv0) * 3072 + sd0);
      u16x8 v1 = *(const u16x8*)(Vg + (size_t)(t * 64 + skv0 + 1) * 3072 + sd0);
#pragma unroll
      for (int i = 0; i < 8; i++) {
        const int d = sd0 + i;
        const u32 pack = (u32)v0[i] | ((u32)v1[i] << 16);
        *(u32*)&Vt[d * 64 + (((skv0 >> 3) ^ (d & 7)) << 3) + (skv0 & 7)] = pack;
      }
    }
    __syncthreads();  // K/Vt visible
    // ---- S = Q * K^T  (D: row q = g*4+r, col kv = l15 within 16-tile)
    f32x4 s[4] = {};
#pragma unroll
    for (int nt = 0; nt < 4; nt++) {
      const int kv = nt * 16 + l15;
#pragma unroll
      for (int ks = 0; ks < 2; ks++) {
        const int dg = ks * 4 + g;
        bf16x8 kf = *(const bf16x8*)&Klds[kv * 64 + ((dg ^ (kv & 7)) << 3)];
        s[nt] = __builtin_amdgcn_mfma_f32_16x16x32_bf16(qf[ks], kf, s[nt], 0, 0, 0);
      }
    }
    // ---- online softmax (row state per r; reduce across 16 lanes of group)
    float pm[4];
#pragma unroll
    for (int r = 0; r < 4; r++)
      pm[r] = fmaxf(fmaxf(s[0][r], s[1][r]), fmaxf(s[2][r], s[3][r]));
#pragma unroll
    for (int m = 1; m < 16; m <<= 1)
#pragma unroll
      for (int r = 0; r < 4; r++) pm[r] = fmaxf(pm[r], __shfl_xor(pm[r], m));
    float alpha[4], psum[4];
#pragma unroll
    for (int r = 0; r < 4; r++) {
      const float mn = fmaxf(mrun[r], pm[r]);
      alpha[r] = exp2f(mrun[r] - mn);
      mrun[r] = mn;
      psum[r] = 0.f;
    }
#pragma unroll
    for (int nt = 0; nt < 4; nt++) {
      const int col = nt * 16 + l15, cg = col >> 3;
#pragma unroll
      for (int r = 0; r < 4; r++) {
        const float p = exp2f(s[nt][r] - mrun[r]);
        psum[r] += p;
        const int prow = g * 4 + r;
        Plds[wid][prow * 64 + ((cg ^ (prow & 7)) << 3) + (col & 7)] = f2b(p);
      }
    }
#pragma unroll
    for (int m = 1; m < 16; m <<= 1)
#pragma unroll
      for (int r = 0; r < 4; r++) psum[r] += __shfl_xor(psum[r], m);
#pragma unroll
    for (int r = 0; r < 4; r++) lrun[r] = lrun[r] * alpha[r] + psum[r];
#pragma unroll
    for (int dt = 0; dt < 4; dt++)
#pragma unroll
      for (int r = 0; r < 4; r++) cacc[dt][r] *= alpha[r];
    // order P ds_writes before P ds_reads (cross-lane via LDS, same wave)
    asm volatile("s_waitcnt lgkmcnt(0)" ::: "memory");
    // ---- PV: ctx += P * V
#pragma unroll
    for (int ks = 0; ks < 2; ks++) {
      bf16x8 pf = *(const bf16x8*)&Plds[wid][l15 * 64 + (((ks * 4 + g) ^ l7) << 3)];
#pragma unroll
      for (int dt = 0; dt < 4; dt++) {
        const int d = dt * 16 + l15;
        const int kg = ks * 4 + g;
        bf16x8 vf = *(const bf16x8*)&Vt[d * 64 + ((kg ^ (d & 7)) << 3)];
        cacc[dt] = __builtin_amdgcn_mfma_f32_16x16x32_bf16(pf, vf, cacc[dt], 0, 0, 0);
      }
    }
  }
  // ---- normalize + write ctx (bf16)
#pragma unroll
  for (int r = 0; r < 4; r++) {
    const float inv = 1.f / lrun[r];
    const int orow = b * 2048 + qt * 64 + wid * 16 + g * 4 + r;
#pragma unroll
    for (int dt = 0; dt < 4; dt++) {
      const int ocol = h * 64 + dt * 16 + l15;
      ctx[(size_t)orow * 1024 + ocol] = f2b(cacc[dt][r] * inv);
    }
  }
}

// ---------------------------------------------------------------------------
extern "C" void kernel_launch(void* const* d_in, const int* in_sizes, int n_in,
                              void* d_out, int out_size, void* d_ws, size_t ws_size,
                              hipStream_t stream) {
  const float* x = (const float*)d_in[0];
  const float* ln1g = (const float*)d_in[1];
  const float* ln1b = (const float*)d_in[2];
  const float* ln2g = (const float*)d_in[3];
  const float* ln2b = (const float*)d_in[4];
  const float* Wq = (const float*)d_in[5];
  const float* bq = (const float*)d_in[6];
  const float* Wk = (const float*)d_in[7];
  const float* bk = (const float*)d_in[8];
  const float* Wv = (const float*)d_in[9];
  const float* bv = (const float*)d_in[10];
  const float* Wo = (const float*)d_in[11];
  const float* bo = (const float*)d_in[12];
  const float* W1 = (const float*)d_in[13];
  const float* b1 = (const float*)d_in[14];
  const float* W2 = (const float*)d_in[15];
  const float* b2 = (const float*)d_in[16];

  char* ws = (char*)d_ws;
  // layout (bytes, all 256-aligned):
  u16* WqkvT = (u16*)(ws + 0);          //  3072*1024 bf16  = 6.29 MB
  u16* WoT = (u16*)(ws + 6291456);      //  1024*1024 bf16  = 2.10 MB
  u16* W1T = (u16*)(ws + 8388608);      //  4096*1024 bf16  = 8.39 MB
  u16* W2T = (u16*)(ws + 16777216);     //  1024*4096 bf16  = 8.39 MB
  u16* xn = (u16*)(ws + 25165824);      //  8192*1024 bf16 (xn1, reused xn2)
  float* x2 = (float*)(ws + 41943040);  //  8192*1024 f32
  u16* ctx = (u16*)(ws + 75497472);     //  8192*1024 bf16
  u16* big = (u16*)(ws + 92274688);     //  QKV 50.3MB then h 67.1MB (union)
  u16* QKVb = big;
  u16* hbuf = big;
  float* outF = (float*)d_out;

  const dim3 tb(32, 8);
  // weight convert+transpose -> BT (bf16 [N][K])
  transpose_cvt<<<dim3(32, 32), tb, 0, stream>>>(Wq, WqkvT, 1024, 1024);
  transpose_cvt<<<dim3(32, 32), tb, 0, stream>>>(Wk, WqkvT + 1024 * 1024, 1024, 1024);
  transpose_cvt<<<dim3(32, 32), tb, 0, stream>>>(Wv, WqkvT + 2048 * 1024, 1024, 1024);
  transpose_cvt<<<dim3(32, 32), tb, 0, stream>>>(Wo, WoT, 1024, 1024);
  transpose_cvt<<<dim3(128, 32), tb, 0, stream>>>(W1, W1T, 1024, 4096);
  transpose_cvt<<<dim3(32, 128), tb, 0, stream>>>(W2, W2T, 4096, 1024);

  // LN1
  ln_fwd<<<dim3(2048), dim3(256), 0, stream>>>(x, ln1g, ln1b, xn);
  // QKV fused GEMM (Q scaled by 0.125*log2e)
  gemm_bt<0><<<dim3(24, 64), dim3(256), 0, stream>>>(xn, WqkvT, bq, bk, bv, nullptr,
                                                     (void*)QKVb, 8192, 3072, 1024);
  // attention
  attn_fwd<<<dim3(32, 16, 4), dim3(256), 0, stream>>>(QKVb, ctx);
  // Wo + residual -> x2 (f32)
  gemm_bt<2><<<dim3(8, 64), dim3(256), 0, stream>>>(ctx, WoT, bo, nullptr, nullptr, x,
                                                    (void*)x2, 8192, 1024, 1024);
  // LN2
  ln_fwd<<<dim3(2048), dim3(256), 0, stream>>>(x2, ln2g, ln2b, xn);
  // FFN1 (ReLU)
  gemm_bt<1><<<dim3(32, 64), dim3(256), 0, stream>>>(xn, W1T, b1, nullptr, nullptr,
                                                     nullptr, (void*)hbuf, 8192, 4096, 1024);
  // FFN2 + residual -> out (f32)
  gemm_bt<2><<<dim3(8, 64), dim3(256), 0, stream>>>(hbuf, W2T, b2, nullptr, nullptr, x2,
                                                    (void*)outF, 8192, 1024, 4096);
}

// Round 2
// 618.613 us; speedup vs baseline: 1.1568x; 1.1568x over previous
//
#include <hip/hip_runtime.h>
#include <cstdint>

typedef unsigned short u16;
typedef unsigned int u32;
typedef __bf16 bf16x8 __attribute__((ext_vector_type(8)));
typedef float f32x4 __attribute__((ext_vector_type(4)));
typedef u16 u16x8 __attribute__((ext_vector_type(8)));
typedef u32 u32x2 __attribute__((ext_vector_type(2)));

#define GLOBAL_AS __attribute__((address_space(1)))
#define LDS_AS __attribute__((address_space(3)))

// fp32 -> bf16 (RNE)
__device__ __forceinline__ u16 f2b(float f) {
  u32 u = __builtin_bit_cast(u32, f);
  u += 0x7fffu + ((u >> 16) & 1u);
  return (u16)(u >> 16);
}

// ---------------------------------------------------------------------------
// Tiled transpose + fp32->bf16 convert: out[n*K + k] = bf16(in[k*N + n])
// block (32,8), grid (N/32, K/32)
// ---------------------------------------------------------------------------
__global__ void transpose_cvt(const float* __restrict__ in, u16* __restrict__ out,
                              int K, int N) {
  __shared__ float tile[32][33];
  const int tx = threadIdx.x, ty = threadIdx.y;
  const int n0 = blockIdx.x * 32, k0 = blockIdx.y * 32;
#pragma unroll
  for (int i = 0; i < 4; i++)
    tile[ty + i * 8][tx] = in[(size_t)(k0 + ty + i * 8) * N + n0 + tx];
  __syncthreads();
#pragma unroll
  for (int i = 0; i < 4; i++)
    out[(size_t)(n0 + ty + i * 8) * K + k0 + tx] = f2b(tile[tx][ty + i * 8]);
}

// ---------------------------------------------------------------------------
// LayerNorm: one wave per row of 1024 fp32, bf16 out. block 256 = 4 rows.
// ---------------------------------------------------------------------------
__global__ __launch_bounds__(256) void ln_fwd(const float* __restrict__ x,
                                              const float* __restrict__ gamma,
                                              const float* __restrict__ beta,
                                              u16* __restrict__ out) {
  const int wid = threadIdx.x >> 6, lane = threadIdx.x & 63;
  const size_t row = (size_t)blockIdx.x * 4 + wid;
  const float* xr = x + row * 1024;
  float4 v[4];
  float s = 0.f, s2 = 0.f;
#pragma unroll
  for (int i = 0; i < 4; i++) {
    v[i] = *(const float4*)(xr + i * 256 + lane * 4);
    s += v[i].x + v[i].y + v[i].z + v[i].w;
    s2 += v[i].x * v[i].x + v[i].y * v[i].y + v[i].z * v[i].z + v[i].w * v[i].w;
  }
#pragma unroll
  for (int m = 1; m < 64; m <<= 1) {
    s += __shfl_xor(s, m);
    s2 += __shfl_xor(s2, m);
  }
  const float mu = s * (1.f / 1024.f);
  const float var = s2 * (1.f / 1024.f) - mu * mu;
  const float rs = rsqrtf(var + 1e-5f);
  u16* orow = out + row * 1024;
#pragma unroll
  for (int i = 0; i < 4; i++) {
    float4 gv = *(const float4*)(gamma + i * 256 + lane * 4);
    float4 bv = *(const float4*)(beta + i * 256 + lane * 4);
    float y0 = (v[i].x - mu) * rs * gv.x + bv.x;
    float y1 = (v[i].y - mu) * rs * gv.y + bv.y;
    float y2 = (v[i].z - mu) * rs * gv.z + bv.z;
    float y3 = (v[i].w - mu) * rs * gv.w + bv.w;
    uint2 pk;
    pk.x = (u32)f2b(y0) | ((u32)f2b(y1) << 16);
    pk.y = (u32)f2b(y2) | ((u32)f2b(y3) << 16);
    *(uint2*)(orow + i * 256 + lane * 4) = pk;
  }
}

// ---------------------------------------------------------------------------
// GEMM C[M,N] = A[M,K] (bf16, row-major) * BT[N,K] (bf16, row-major) + epilogue
// m97 structure: 128x128 tile, BK=64, 4 waves (2x2), 16x16x32 MFMA,
// global_load_lds width 16, 2-barrier K loop.
// MODE 0: QKV  -> bf16 out = (acc + bias_sel[col]) * (qcols ? 0.125*log2e : 1)
// MODE 1: FFN1 -> bf16 out = relu(acc + b0[col])
// MODE 2: RES  -> f32 out  = acc + b0[col] + res[row,col]
// ---------------------------------------------------------------------------
template <int MODE>
__global__ __launch_bounds__(256) void gemm_bt(
    const u16* __restrict__ A, const u16* __restrict__ BT,
    const float* __restrict__ b0, const float* __restrict__ b1,
    const float* __restrict__ b2, const float* __restrict__ res,
    void* __restrict__ outp, int M, int N, int K) {
  __shared__ __align__(16) u16 Alds[128 * 64];
  __shared__ __align__(16) u16 Blds[128 * 64];
  const int tid = threadIdx.x;
  const int wid = tid >> 6, lane = tid & 63;
  const int wm = wid >> 1, wn = wid & 1;
  const int g = lane >> 4, l15 = lane & 15;
  const int bm = blockIdx.y * 128, bn = blockIdx.x * 128;

  f32x4 acc[4][4] = {};

  const int srow = wid * 32 + (lane >> 3);
  const int scol = (lane & 7) * 8;
  const u16* Ag = A + (size_t)(bm + srow) * K + scol;
  const u16* Bg = BT + (size_t)(bn + srow) * K + scol;

  for (int k0 = 0; k0 < K; k0 += 64) {
    __syncthreads();
#pragma unroll
    for (int i = 0; i < 4; i++)
      __builtin_amdgcn_global_load_lds(
          (const GLOBAL_AS u32*)(Ag + (size_t)(i * 8) * K + k0),
          (LDS_AS u32*)&Alds[(wid * 32 + i * 8) * 64], 16, 0, 0);
#pragma unroll
    for (int i = 0; i < 4; i++)
      __builtin_amdgcn_global_load_lds(
          (const GLOBAL_AS u32*)(Bg + (size_t)(i * 8) * K + k0),
          (LDS_AS u32*)&Blds[(wid * 32 + i * 8) * 64], 16, 0, 0);
    __syncthreads();
#pragma unroll
    for (int ks = 0; ks < 2; ks++) {
      bf16x8 af[4], bfr[4];
#pragma unroll
      for (int mt = 0; mt < 4; mt++)
        af[mt] = *(const bf16x8*)&Alds[(wm * 64 + mt * 16 + l15) * 64 + ks * 32 + g * 8];
#pragma unroll
      for (int nt = 0; nt < 4; nt++)
        bfr[nt] = *(const bf16x8*)&Blds[(wn * 64 + nt * 16 + l15) * 64 + ks * 32 + g * 8];
#pragma unroll
      for (int mt = 0; mt < 4; mt++)
#pragma unroll
        for (int nt = 0; nt < 4; nt++)
          acc[mt][nt] = __builtin_amdgcn_mfma_f32_16x16x32_bf16(
              af[mt], bfr[nt], acc[mt][nt], 0, 0, 0);
    }
  }

  // epilogue
  const float* bias = b0;
  float scale = 1.f;
  if (MODE == 0) {
    bias = (bn < 1024) ? b0 : (bn < 2048 ? b1 : b2);
    if (bn < 1024) scale = 0.18033688011112042f;  // 0.125 * log2(e)
  }
#pragma unroll
  for (int mt = 0; mt < 4; mt++) {
#pragma unroll
    for (int nt = 0; nt < 4; nt++) {
      const int orow = bm + wm * 64 + mt * 16 + g * 4;
      const int ocol = bn + wn * 64 + nt * 16 + l15;
      const float bv = bias[MODE == 0 ? (ocol & 1023) : ocol];
#pragma unroll
      for (int r = 0; r < 4; r++) {
        const float v = acc[mt][nt][r] + bv;
        const size_t oi = (size_t)(orow + r) * N + ocol;
        if (MODE == 0)
          ((u16*)outp)[oi] = f2b(v * scale);
        else if (MODE == 1)
          ((u16*)outp)[oi] = f2b(v > 0.f ? v : 0.f);
        else
          ((float*)outp)[oi] = v + res[oi];
      }
    }
  }
}

// ---------------------------------------------------------------------------
// Flash attention fwd, swapped-operand design.
// QKV [8192][3072] bf16 (Q|K|V blocks of 1024 cols; head h = 64 cols).
// Q pre-scaled by 0.125*log2e, so P = exp2(S - m).
// Block = (qt, h, b): 64 q-rows, 4 waves x 16 q-rows. KV tile = 64.
//
// QK^T swapped: S^T = mfma_16x16x32(A=K, B=Q) -> lane owns q = lane&15,
//   kv = nt*16 + g*4 + r  (g = lane>>4). Softmax state (m,l,alpha) is one
//   scalar per lane; row-reduce = 15 fmax + shfl_xor(16,32).
// PV swapped:   O^T = mfma_16x16x16(A=V^T via ds_read_b64_tr_b16, B=P).
//   K=16 B-frag layout (k = g*4+j) == swapped-QK^T ownership -> P packs
//   straight from f32 regs via v_cvt_pk_bf16_f32, zero exchange, no P LDS.
// K LDS [64][64] XOR-swizzled via pre-swizzled global_load_lds source.
// V LDS subtiled [kv/4][d/16][4][16] (tr-read gather = addr + {0,32,64,96}B),
//   staged linearly by global_load_lds with per-lane permuted source.
// Double-buffered K/V, 1 barrier per tile, stage(t+1) issued before compute.
// ---------------------------------------------------------------------------
__global__ __launch_bounds__(256) void attn_fwd(const u16* __restrict__ QKV,
                                                u16* __restrict__ ctx) {
  __shared__ __align__(16) u16 Klds[2][64 * 64];
  __shared__ __align__(16) u16 Vlds[2][64 * 64];
  const int tid = threadIdx.x;
  const int wid = tid >> 6, lane = tid & 63;
  const int g = lane >> 4, l15 = lane & 15;
  const int qt = blockIdx.x, h = blockIdx.y, b = blockIdx.z;

  // Q fragments (B-operand of swapped QK^T): lane holds q-row l15,
  // d = ks*32 + g*8 + j  -- identical load to the A-frag form.
  const u16* Qbase = QKV + (size_t)(b * 2048 + qt * 64 + wid * 16) * 3072 + h * 64;
  bf16x8 qf[2];
#pragma unroll
  for (int ks = 0; ks < 2; ks++)
    qf[ks] = *(const bf16x8*)(Qbase + (size_t)l15 * 3072 + ks * 32 + g * 8);

  const u16* Kg = QKV + (size_t)(b * 2048) * 3072 + 1024 + h * 64;
  const u16* Vg = QKV + (size_t)(b * 2048) * 3072 + 2048 + h * 64;

  // staging constants. granule p = tid + 256*i (16B granules, 512 per tile)
  // K: kv = p>>3, dgrp = p&7, source col = (dgrp ^ (kv&7))*8 (read-side XOR swizzle)
  // V: subtiled dest; kv = (p>>5)*4 + ((p>>1)&3), d0 = ((p>>3)&3)*16 + (p&1)*8
  int kvK[2], colK[2], kvV[2], d0V[2];
#pragma unroll
  for (int i = 0; i < 2; i++) {
    const int p = tid + 256 * i;
    kvK[i] = p >> 3;
    colK[i] = ((p & 7) ^ (kvK[i] & 7)) << 3;
    kvV[i] = ((p >> 5) << 2) | ((p >> 1) & 3);
    d0V[i] = (((p >> 3) & 3) << 4) | ((p & 1) << 3);
  }

#define STAGE(bufidx, tt)                                                          \
  do {                                                                             \
    const size_t roff = (size_t)(tt) * 64 * 3072;                                  \
    _Pragma("unroll") for (int i = 0; i < 2; i++) {                                \
      __builtin_amdgcn_global_load_lds(                                            \
          (const GLOBAL_AS u32*)(Kg + roff + (size_t)kvK[i] * 3072 + colK[i]),     \
          (LDS_AS u32*)&Klds[bufidx][(i * 256 + wid * 64) * 8], 16, 0, 0);         \
      __builtin_amdgcn_global_load_lds(                                            \
          (const GLOBAL_AS u32*)(Vg + roff + (size_t)kvV[i] * 3072 + d0V[i]),      \
          (LDS_AS u32*)&Vlds[bufidx][(i * 256 + wid * 64) * 8], 16, 0, 0);         \
    }                                                                              \
  } while (0)

#define TRISSUE(dst, dtc)                                                          \
  do {                                                                             \
    _Pragma("unroll") for (int nt = 0; nt < 4; nt++) {                             \
      const u32 a_ = vb + (u32)((((nt * 4 + g) * 4 + (dtc)) << 7) + (l15 << 1));   \
      asm volatile("ds_read_b64_tr_b16 %0, %1" : "=v"(dst[nt]) : "v"(a_)           \
                   : "memory");                                                    \
    }                                                                              \
  } while (0)

  float mrun = -3.0e38f, lrun = 0.f;
  f32x4 cacc[4] = {};

  STAGE(0, 0);
  int cur = 0;
  for (int t = 0; t < 32; t++) {
    __syncthreads();  // drains vmcnt: buf[cur] ready; all waves done with buf[cur^1]
    if (t < 31) STAGE(cur ^ 1, t + 1);

    // ---- S^T = K * Q^T (per nt-tile: lane -> q=l15, kv=nt*16+g*4+r)
    const u16* Kc = &Klds[cur][0];
    f32x4 s4[4] = {};
#pragma unroll
    for (int nt = 0; nt < 4; nt++) {
      const int kv = nt * 16 + l15;
      const int sw = kv & 7;
#pragma unroll
      for (int ks = 0; ks < 2; ks++) {
        bf16x8 kf = *(const bf16x8*)&Kc[kv * 64 + (((ks * 4 + g) ^ sw) << 3)];
        s4[nt] = __builtin_amdgcn_mfma_f32_16x16x32_bf16(kf, qf[ks], s4[nt], 0, 0, 0);
      }
    }

    // ---- online softmax, fully per-lane (q = l15)
    float pm = s4[0][0];
#pragma unroll
    for (int nt = 0; nt < 4; nt++)
#pragma unroll
      for (int r = 0; r < 4; r++) pm = fmaxf(pm, s4[nt][r]);
    pm = fmaxf(pm, __shfl_xor(pm, 16));
    pm = fmaxf(pm, __shfl_xor(pm, 32));
    const float mn = fmaxf(mrun, pm);
    const float alpha = exp2f(mrun - mn);
    mrun = mn;

    float psum = 0.f;
    u32 w[4][2];
#pragma unroll
    for (int nt = 0; nt < 4; nt++) {
      const float p0 = exp2f(s4[nt][0] - mn);
      const float p1 = exp2f(s4[nt][1] - mn);
      const float p2 = exp2f(s4[nt][2] - mn);
      const float p3 = exp2f(s4[nt][3] - mn);
      psum += (p0 + p1) + (p2 + p3);
      asm("v_cvt_pk_bf16_f32 %0, %1, %2" : "=v"(w[nt][0]) : "v"(p0), "v"(p1));
      asm("v_cvt_pk_bf16_f32 %0, %1, %2" : "=v"(w[nt][1]) : "v"(p2), "v"(p3));
    }
    psum += __shfl_xor(psum, 16);
    psum += __shfl_xor(psum, 32);
    lrun = lrun * alpha + psum;
#pragma unroll
    for (int dt = 0; dt < 4; dt++) cacc[dt] *= alpha;

    // ---- O^T += V^T * P^T  (16x16x16; A via tr-read, B = packed P)
    const u32 vb = (u32)(uintptr_t)(const LDS_AS u16*)&Vlds[cur][0];
    u32x2 vf[2][4];
    TRISSUE(vf[0], 0);
#pragma unroll
    for (int dt = 0; dt < 4; dt++) {
      if (dt < 3) TRISSUE(vf[(dt + 1) & 1], dt + 1);
      if (dt < 3)
        asm volatile("s_waitcnt lgkmcnt(4)" ::: "memory");
      else
        asm volatile("s_waitcnt lgkmcnt(0)" ::: "memory");
      __builtin_amdgcn_sched_barrier(0);
#pragma unroll
      for (int nt = 0; nt < 4; nt++) {
        const u32x2 pf = {w[nt][0], w[nt][1]};
        asm volatile("v_mfma_f32_16x16x16_bf16 %0, %1, %2, %0"
                     : "+v"(cacc[dt])
                     : "v"(vf[dt & 1][nt]), "v"(pf));
      }
    }
    cur ^= 1;
  }
#undef STAGE
#undef TRISSUE

  // MFMA->VALU read spacing
  asm volatile("s_nop 7" :::);
  asm volatile("s_nop 7" :::);

  // ---- normalize + write ctx: lane holds O[q=l15][d = dt*16 + g*4 + r]
  const float inv = 1.f / lrun;
  u16* op = ctx + (size_t)(b * 2048 + qt * 64 + wid * 16 + l15) * 1024 + h * 64 + g * 4;
#pragma unroll
  for (int dt = 0; dt < 4; dt++) {
    u32 lo, hi;
    const float c0 = cacc[dt][0] * inv, c1 = cacc[dt][1] * inv;
    const float c2 = cacc[dt][2] * inv, c3 = cacc[dt][3] * inv;
    asm("v_cvt_pk_bf16_f32 %0, %1, %2" : "=v"(lo) : "v"(c0), "v"(c1));
    asm("v_cvt_pk_bf16_f32 %0, %1, %2" : "=v"(hi) : "v"(c2), "v"(c3));
    *(u32x2*)(op + dt * 16) = (u32x2){lo, hi};
  }
}

// ---------------------------------------------------------------------------
extern "C" void kernel_launch(void* const* d_in, const int* in_sizes, int n_in,
                              void* d_out, int out_size, void* d_ws, size_t ws_size,
                              hipStream_t stream) {
  const float* x = (const float*)d_in[0];
  const float* ln1g = (const float*)d_in[1];
  const float* ln1b = (const float*)d_in[2];
  const float* ln2g = (const float*)d_in[3];
  const float* ln2b = (const float*)d_in[4];
  const float* Wq = (const float*)d_in[5];
  const float* bq = (const float*)d_in[6];
  const float* Wk = (const float*)d_in[7];
  const float* bk = (const float*)d_in[8];
  const float* Wv = (const float*)d_in[9];
  const float* bv = (const float*)d_in[10];
  const float* Wo = (const float*)d_in[11];
  const float* bo = (const float*)d_in[12];
  const float* W1 = (const float*)d_in[13];
  const float* b1 = (const float*)d_in[14];
  const float* W2 = (const float*)d_in[15];
  const float* b2 = (const float*)d_in[16];

  char* ws = (char*)d_ws;
  // layout (bytes, all 256-aligned):
  u16* WqkvT = (u16*)(ws + 0);          //  3072*1024 bf16  = 6.29 MB
  u16* WoT = (u16*)(ws + 6291456);      //  1024*1024 bf16  = 2.10 MB
  u16* W1T = (u16*)(ws + 8388608);      //  4096*1024 bf16  = 8.39 MB
  u16* W2T = (u16*)(ws + 16777216);     //  1024*4096 bf16  = 8.39 MB
  u16* xn = (u16*)(ws + 25165824);      //  8192*1024 bf16 (xn1, reused xn2)
  float* x2 = (float*)(ws + 41943040);  //  8192*1024 f32
  u16* ctx = (u16*)(ws + 75497472);     //  8192*1024 bf16
  u16* big = (u16*)(ws + 92274688);     //  QKV 50.3MB then h 67.1MB (union)
  u16* QKVb = big;
  u16* hbuf = big;
  float* outF = (float*)d_out;

  const dim3 tb(32, 8);
  // weight convert+transpose -> BT (bf16 [N][K])
  transpose_cvt<<<dim3(32, 32), tb, 0, stream>>>(Wq, WqkvT, 1024, 1024);
  transpose_cvt<<<dim3(32, 32), tb, 0, stream>>>(Wk, WqkvT + 1024 * 1024, 1024, 1024);
  transpose_cvt<<<dim3(32, 32), tb, 0, stream>>>(Wv, WqkvT + 2048 * 1024, 1024, 1024);
  transpose_cvt<<<dim3(32, 32), tb, 0, stream>>>(Wo, WoT, 1024, 1024);
  transpose_cvt<<<dim3(128, 32), tb, 0, stream>>>(W1, W1T, 1024, 4096);
  transpose_cvt<<<dim3(32, 128), tb, 0, stream>>>(W2, W2T, 4096, 1024);

  // LN1
  ln_fwd<<<dim3(2048), dim3(256), 0, stream>>>(x, ln1g, ln1b, xn);
  // QKV fused GEMM (Q scaled by 0.125*log2e)
  gemm_bt<0><<<dim3(24, 64), dim3(256), 0, stream>>>(xn, WqkvT, bq, bk, bv, nullptr,
                                                     (void*)QKVb, 8192, 3072, 1024);
  // attention
  attn_fwd<<<dim3(32, 16, 4), dim3(256), 0, stream>>>(QKVb, ctx);
  // Wo + residual -> x2 (f32)
  gemm_bt<2><<<dim3(8, 64), dim3(256), 0, stream>>>(ctx, WoT, bo, nullptr, nullptr, x,
                                                    (void*)x2, 8192, 1024, 1024);
  // LN2
  ln_fwd<<<dim3(2048), dim3(256), 0, stream>>>(x2, ln2g, ln2b, xn);
  // FFN1 (ReLU)
  gemm_bt<1><<<dim3(32, 64), dim3(256), 0, stream>>>(xn, W1T, b1, nullptr, nullptr,
                                                     nullptr, (void*)hbuf, 8192, 4096, 1024);
  // FFN2 + residual -> out (f32)
  gemm_bt<2><<<dim3(8, 64), dim3(256), 0, stream>>>(hbuf, W2T, b2, nullptr, nullptr, x2,
                                                    (void*)outF, 8192, 1024, 4096);
}

// Round 5
// 586.678 us; speedup vs baseline: 1.2197x; 1.0544x over previous
//
#include <hip/hip_runtime.h>
#include <cstdint>

typedef unsigned short u16;
typedef unsigned int u32;
typedef __bf16 bf16x8 __attribute__((ext_vector_type(8)));
typedef float f32x4 __attribute__((ext_vector_type(4)));
typedef u16 u16x8 __attribute__((ext_vector_type(8)));
typedef u32 u32x2 __attribute__((ext_vector_type(2)));

#define GLOBAL_AS __attribute__((address_space(1)))
#define LDS_AS __attribute__((address_space(3)))

// fp32 -> bf16 (RNE)
__device__ __forceinline__ u16 f2b(float f) {
  u32 u = __builtin_bit_cast(u32, f);
  u += 0x7fffu + ((u >> 16) & 1u);
  return (u16)(u >> 16);
}

// ---------------------------------------------------------------------------
// Tiled transpose + fp32->bf16 convert: out[n*K + k] = bf16(in[k*N + n])
// block (32,8), grid (N/32, K/32)
// ---------------------------------------------------------------------------
__global__ void transpose_cvt(const float* __restrict__ in, u16* __restrict__ out,
                              int K, int N) {
  __shared__ float tile[32][33];
  const int tx = threadIdx.x, ty = threadIdx.y;
  const int n0 = blockIdx.x * 32, k0 = blockIdx.y * 32;
#pragma unroll
  for (int i = 0; i < 4; i++)
    tile[ty + i * 8][tx] = in[(size_t)(k0 + ty + i * 8) * N + n0 + tx];
  __syncthreads();
#pragma unroll
  for (int i = 0; i < 4; i++)
    out[(size_t)(n0 + ty + i * 8) * K + k0 + tx] = f2b(tile[tx][ty + i * 8]);
}

// ---------------------------------------------------------------------------
// LayerNorm: one wave per row of 1024 fp32, bf16 out. block 256 = 4 rows.
// ---------------------------------------------------------------------------
__global__ __launch_bounds__(256) void ln_fwd(const float* __restrict__ x,
                                              const float* __restrict__ gamma,
                                              const float* __restrict__ beta,
                                              u16* __restrict__ out) {
  const int wid = threadIdx.x >> 6, lane = threadIdx.x & 63;
  const size_t row = (size_t)blockIdx.x * 4 + wid;
  const float* xr = x + row * 1024;
  float4 v[4];
  float s = 0.f, s2 = 0.f;
#pragma unroll
  for (int i = 0; i < 4; i++) {
    v[i] = *(const float4*)(xr + i * 256 + lane * 4);
    s += v[i].x + v[i].y + v[i].z + v[i].w;
    s2 += v[i].x * v[i].x + v[i].y * v[i].y + v[i].z * v[i].z + v[i].w * v[i].w;
  }
#pragma unroll
  for (int m = 1; m < 64; m <<= 1) {
    s += __shfl_xor(s, m);
    s2 += __shfl_xor(s2, m);
  }
  const float mu = s * (1.f / 1024.f);
  const float var = s2 * (1.f / 1024.f) - mu * mu;
  const float rs = rsqrtf(var + 1e-5f);
  u16* orow = out + row * 1024;
#pragma unroll
  for (int i = 0; i < 4; i++) {
    float4 gv = *(const float4*)(gamma + i * 256 + lane * 4);
    float4 bv = *(const float4*)(beta + i * 256 + lane * 4);
    float y0 = (v[i].x - mu) * rs * gv.x + bv.x;
    float y1 = (v[i].y - mu) * rs * gv.y + bv.y;
    float y2 = (v[i].z - mu) * rs * gv.z + bv.z;
    float y3 = (v[i].w - mu) * rs * gv.w + bv.w;
    uint2 pk;
    pk.x = (u32)f2b(y0) | ((u32)f2b(y1) << 16);
    pk.y = (u32)f2b(y2) | ((u32)f2b(y3) << 16);
    *(uint2*)(orow + i * 256 + lane * 4) = pk;
  }
}

// ---------------------------------------------------------------------------
// 8-phase-style GEMM: C[M,N] = A[M,K] * BT[N,K] (both bf16 row-major).
// BM = MF*32 (256 or 128), BN = 256, BK = 64. 8 waves (2M x 4N), 512 thr.
// LDS XOR-swizzle: LDS[row][slot] = src[row][slot ^ (row&7)] via pre-swizzled
// global_load_lds SOURCE; ds_reads apply the same XOR (both-sides, rule 21).
// Double-buffered; counted vmcnt (own-slice coverage before joining barrier);
// raw s_barrier; setprio around MFMA clusters; bijective XCD swizzle (%8==0).
// MODE 0: QKV  -> bf16 out = (acc + bias_sel[col]) * (q cols ? 0.125*log2e : 1)
// MODE 1: FFN1 -> bf16 out = relu(acc + b0[col])
// MODE 2: RES  -> f32 out  = acc + b0[col] + res[row,col]
// Schedule audit (per-wave loads L = AL+4): prologue stages t0,t1 (2L out),
// vmcnt(L) -> own t0 slice landed -> barrier -> all t0 landed. Boundary at
// end of tile t: barrier (all done READING buf b) -> stage t+2 into buf b
// (2L out) -> vmcnt(L) -> own t+1 slice landed -> barrier -> buf b^1 valid.
// WAR safe: no wave issues writes to buf b until every wave passed barrier 1.
// ---------------------------------------------------------------------------
template <int MF, int MODE>
__global__ __launch_bounds__(512, 2) void gemm8p(
    const u16* __restrict__ A, const u16* __restrict__ BT,
    const float* __restrict__ b0, const float* __restrict__ b1,
    const float* __restrict__ b2, const float* __restrict__ res,
    void* __restrict__ outp, int M, int N, int K, int gridN) {
  constexpr int BM = MF * 32;
  constexpr int AL = BM / 64;  // A-loads per wave per K-tile (4 or 2)
  __shared__ __align__(16) u16 Albuf[2][BM * 64];
  __shared__ __align__(16) u16 Blbuf[2][256 * 64];

  const int tid = threadIdx.x;
  const int lane = tid & 63, wid = tid >> 6;
  const int wr = wid >> 2, wc = wid & 3;
  const int g = lane >> 4, l15 = lane & 15;
  const int l8r = lane >> 3, l8c = lane & 7;

  const int nwg = gridDim.x;
  const int bid = blockIdx.x;
  const int tile = (bid & 7) * (nwg >> 3) + (bid >> 3);
  const int tm = tile / gridN, tn = tile - tm * gridN;
  const int bm = tm * BM, bn = tn * 256;

  // staging source (pre-swizzled): granule slot l8c XOR row&7 (=l8r)
  const int scol = 8 * (l8c ^ l8r);
  const u16* Ab = A + (size_t)(bm + wid * (AL * 8) + l8r) * K + scol;
  const u16* Bb = BT + (size_t)(bn + wid * 32 + l8r) * K + scol;

#define STAGE(bb, k0)                                                            \
  do {                                                                           \
    _Pragma("unroll") for (int i = 0; i < AL; i++)                               \
        __builtin_amdgcn_global_load_lds(                                        \
            (const GLOBAL_AS u32*)(Ab + (size_t)i * 8 * K + (k0)),               \
            (LDS_AS u32*)&Albuf[bb][(wid * AL + i) * 512], 16, 0, 0);            \
    _Pragma("unroll") for (int i = 0; i < 4; i++)                                \
        __builtin_amdgcn_global_load_lds(                                        \
            (const GLOBAL_AS u32*)(Bb + (size_t)i * 8 * K + (k0)),               \
            (LDS_AS u32*)&Blbuf[bb][(wid * 4 + i) * 512], 16, 0, 0);             \
  } while (0)

#define VMCNT_STEADY()                                                           \
  do {                                                                           \
    if constexpr (MF == 8)                                                       \
      asm volatile("s_waitcnt vmcnt(8)" ::: "memory");                           \
    else                                                                         \
      asm volatile("s_waitcnt vmcnt(6)" ::: "memory");                           \
  } while (0)

  f32x4 acc[MF][4] = {};
  const int NT = K >> 6;

  // frag-read constants (elem units); wanted k-group dg stored at slot
  // dg ^ (row&7); row&7 == l15&7 for all fragment rows.
  const int arow0 = (wr * (MF * 16) + l15) * 64;
  const int brow0 = (wc * 64 + l15) * 64;
  const int csw[2] = {8 * ((0 * 4 + g) ^ (l15 & 7)), 8 * ((1 * 4 + g) ^ (l15 & 7))};

  // prologue: stage tiles 0 and 1
  STAGE(0, 0);
  STAGE(1, 64);
  VMCNT_STEADY();
  __builtin_amdgcn_sched_barrier(0);
  __builtin_amdgcn_s_barrier();

  for (int t = 0; t < NT; t++) {
    const int b = t & 1;
    const u16* Alb = &Albuf[b][0];
    const u16* Blb = &Blbuf[b][0];
#pragma unroll
    for (int q = 0; q < 4; q++) {
      const int mh = q & 1, ks = q >> 1;
      bf16x8 af[MF / 2], bf[4];
#pragma unroll
      for (int i = 0; i < MF / 2; i++)
        af[i] = *(const bf16x8*)&Alb[arow0 + (mh * (MF / 2) + i) * (16 * 64) + csw[ks]];
#pragma unroll
      for (int nt = 0; nt < 4; nt++)
        bf[nt] = *(const bf16x8*)&Blb[brow0 + nt * (16 * 64) + csw[ks]];
      __builtin_amdgcn_s_setprio(1);
#pragma unroll
      for (int i = 0; i < MF / 2; i++)
#pragma unroll
        for (int nt = 0; nt < 4; nt++)
          acc[mh * (MF / 2) + i][nt] = __builtin_amdgcn_mfma_f32_16x16x32_bf16(
              af[i], bf[nt], acc[mh * (MF / 2) + i][nt], 0, 0, 0);
      __builtin_amdgcn_s_setprio(0);
    }
    if (t + 1 < NT) {
      __builtin_amdgcn_s_barrier();  // all waves done reading buf b
      if (t + 2 < NT) {
        STAGE(b, (t + 2) * 64);
        VMCNT_STEADY();  // own slice of tile t+1 landed
      } else {
        asm volatile("s_waitcnt vmcnt(0)" ::: "memory");
      }
      __builtin_amdgcn_sched_barrier(0);
      __builtin_amdgcn_s_barrier();  // join: buf b^1 valid for everyone
    }
  }
#undef STAGE
#undef VMCNT_STEADY

  // epilogue
  const int orow0 = bm + wr * (MF * 16);
  const int ocol0 = bn + wc * 64;
#pragma unroll
  for (int mf = 0; mf < MF; mf++) {
#pragma unroll
    for (int nt = 0; nt < 4; nt++) {
      const int orow = orow0 + mf * 16 + g * 4;
      const int ocol = ocol0 + nt * 16 + l15;
      float bv, scale = 1.f;
      if (MODE == 0) {
        bv = (ocol < 1024) ? b0[ocol] : (ocol < 2048 ? b1[ocol - 1024] : b2[ocol - 2048]);
        if (ocol < 1024) scale = 0.18033688011112042f;  // 0.125 * log2(e)
      } else {
        bv = b0[ocol];
      }
#pragma unroll
      for (int r = 0; r < 4; r++) {
        const float v = acc[mf][nt][r] + bv;
        const size_t oi = (size_t)(orow + r) * N + ocol;
        if (MODE == 0)
          ((u16*)outp)[oi] = f2b(v * scale);
        else if (MODE == 1)
          ((u16*)outp)[oi] = f2b(v > 0.f ? v : 0.f);
        else
          ((float*)outp)[oi] = v + res[oi];
      }
    }
  }
}

// ---------------------------------------------------------------------------
// Flash attention fwd, swapped-operand design — BIT-IDENTICAL to the round-2
// green version (164 us, MfmaUtil 27.7). The round-3 additions (l-sum MFMA,
// max3 asm, defer-max, unroll-2) are reverted: the l-sum inline-asm MFMA read
// its cvt_pk-written operand with ~0 instruction spacing; VALU-write ->
// MFMA-read needs ~2 wait states and the hazard recognizer cannot see MFMAs
// inside inline asm -> garbage operand -> NaN. Re-add later with explicit
// spacing if attn remains the bottleneck.
// ---------------------------------------------------------------------------
__global__ __launch_bounds__(256) void attn_fwd(const u16* __restrict__ QKV,
                                                u16* __restrict__ ctx) {
  __shared__ __align__(16) u16 Klds[2][64 * 64];
  __shared__ __align__(16) u16 Vlds[2][64 * 64];
  const int tid = threadIdx.x;
  const int wid = tid >> 6, lane = tid & 63;
  const int g = lane >> 4, l15 = lane & 15;
  const int qt = blockIdx.x, h = blockIdx.y, b = blockIdx.z;

  const u16* Qbase = QKV + (size_t)(b * 2048 + qt * 64 + wid * 16) * 3072 + h * 64;
  bf16x8 qf[2];
#pragma unroll
  for (int ks = 0; ks < 2; ks++)
    qf[ks] = *(const bf16x8*)(Qbase + (size_t)l15 * 3072 + ks * 32 + g * 8);

  const u16* Kg = QKV + (size_t)(b * 2048) * 3072 + 1024 + h * 64;
  const u16* Vg = QKV + (size_t)(b * 2048) * 3072 + 2048 + h * 64;

  int kvK[2], colK[2], kvV[2], d0V[2];
#pragma unroll
  for (int i = 0; i < 2; i++) {
    const int p = tid + 256 * i;
    kvK[i] = p >> 3;
    colK[i] = ((p & 7) ^ (kvK[i] & 7)) << 3;
    kvV[i] = ((p >> 5) << 2) | ((p >> 1) & 3);
    d0V[i] = (((p >> 3) & 3) << 4) | ((p & 1) << 3);
  }

#define STAGE(bufidx, tt)                                                          \
  do {                                                                             \
    const size_t roff = (size_t)(tt) * 64 * 3072;                                  \
    _Pragma("unroll") for (int i = 0; i < 2; i++) {                                \
      __builtin_amdgcn_global_load_lds(                                            \
          (const GLOBAL_AS u32*)(Kg + roff + (size_t)kvK[i] * 3072 + colK[i]),     \
          (LDS_AS u32*)&Klds[bufidx][(i * 256 + wid * 64) * 8], 16, 0, 0);         \
      __builtin_amdgcn_global_load_lds(                                            \
          (const GLOBAL_AS u32*)(Vg + roff + (size_t)kvV[i] * 3072 + d0V[i]),      \
          (LDS_AS u32*)&Vlds[bufidx][(i * 256 + wid * 64) * 8], 16, 0, 0);         \
    }                                                                              \
  } while (0)

#define TRISSUE(dst, dtc)                                                          \
  do {                                                                             \
    _Pragma("unroll") for (int nt = 0; nt < 4; nt++) {                             \
      const u32 a_ = vb + (u32)((((nt * 4 + g) * 4 + (dtc)) << 7) + (l15 << 1));   \
      asm volatile("ds_read_b64_tr_b16 %0, %1" : "=v"(dst[nt]) : "v"(a_)           \
                   : "memory");                                                    \
    }                                                                              \
  } while (0)

  float mrun = -3.0e38f, lrun = 0.f;
  f32x4 cacc[4] = {};

  STAGE(0, 0);
  int cur = 0;
  for (int t = 0; t < 32; t++) {
    __syncthreads();  // buf[cur] ready (drains vmcnt); buf[cur^1] free
    if (t < 31) STAGE(cur ^ 1, t + 1);

    // ---- S^T = K * Q^T (lane -> q=l15, kv = nt*16 + g*4 + r)
    const u16* Kc = &Klds[cur][0];
    f32x4 s4[4] = {};
#pragma unroll
    for (int nt = 0; nt < 4; nt++) {
      const int kv = nt * 16 + l15;
      const int sw = kv & 7;
#pragma unroll
      for (int ks = 0; ks < 2; ks++) {
        bf16x8 kf = *(const bf16x8*)&Kc[kv * 64 + (((ks * 4 + g) ^ sw) << 3)];
        s4[nt] = __builtin_amdgcn_mfma_f32_16x16x32_bf16(kf, qf[ks], s4[nt], 0, 0, 0);
      }
    }

    // ---- online softmax, fully per-lane (q = l15)
    float pm = s4[0][0];
#pragma unroll
    for (int nt = 0; nt < 4; nt++)
#pragma unroll
      for (int r = 0; r < 4; r++) pm = fmaxf(pm, s4[nt][r]);
    pm = fmaxf(pm, __shfl_xor(pm, 16));
    pm = fmaxf(pm, __shfl_xor(pm, 32));
    const float mn = fmaxf(mrun, pm);
    const float alpha = exp2f(mrun - mn);
    mrun = mn;

    float psum = 0.f;
    u32 w[4][2];
#pragma unroll
    for (int nt = 0; nt < 4; nt++) {
      const float p0 = exp2f(s4[nt][0] - mn);
      const float p1 = exp2f(s4[nt][1] - mn);
      const float p2 = exp2f(s4[nt][2] - mn);
      const float p3 = exp2f(s4[nt][3] - mn);
      psum += (p0 + p1) + (p2 + p3);
      asm("v_cvt_pk_bf16_f32 %0, %1, %2" : "=v"(w[nt][0]) : "v"(p0), "v"(p1));
      asm("v_cvt_pk_bf16_f32 %0, %1, %2" : "=v"(w[nt][1]) : "v"(p2), "v"(p3));
    }
    psum += __shfl_xor(psum, 16);
    psum += __shfl_xor(psum, 32);
    lrun = lrun * alpha + psum;
#pragma unroll
    for (int dt = 0; dt < 4; dt++) cacc[dt] *= alpha;

    // ---- O^T += V^T * P^T  (16x16x16; A via tr-read, B = packed P)
    const u32 vb = (u32)(uintptr_t)(const LDS_AS u16*)&Vlds[cur][0];
    u32x2 vf[2][4];
    TRISSUE(vf[0], 0);
#pragma unroll
    for (int dt = 0; dt < 4; dt++) {
      if (dt < 3) TRISSUE(vf[(dt + 1) & 1], dt + 1);
      if (dt < 3)
        asm volatile("s_waitcnt lgkmcnt(4)" ::: "memory");
      else
        asm volatile("s_waitcnt lgkmcnt(0)" ::: "memory");
      __builtin_amdgcn_sched_barrier(0);
#pragma unroll
      for (int nt = 0; nt < 4; nt++) {
        const u32x2 pf = {w[nt][0], w[nt][1]};
        asm volatile("v_mfma_f32_16x16x16_bf16 %0, %1, %2, %0"
                     : "+v"(cacc[dt])
                     : "v"(vf[dt & 1][nt]), "v"(pf));
      }
    }
    cur ^= 1;
  }
#undef STAGE
#undef TRISSUE

  // MFMA->VALU read spacing
  asm volatile("s_nop 7" :::);
  asm volatile("s_nop 7" :::);

  // ---- normalize + write ctx: lane holds O[q=l15][d = dt*16 + g*4 + r]
  const float inv = 1.f / lrun;
  u16* op = ctx + (size_t)(b * 2048 + qt * 64 + wid * 16 + l15) * 1024 + h * 64 + g * 4;
#pragma unroll
  for (int dt = 0; dt < 4; dt++) {
    u32 lo, hi;
    const float c0 = cacc[dt][0] * inv, c1 = cacc[dt][1] * inv;
    const float c2 = cacc[dt][2] * inv, c3 = cacc[dt][3] * inv;
    asm("v_cvt_pk_bf16_f32 %0, %1, %2" : "=v"(lo) : "v"(c0), "v"(c1));
    asm("v_cvt_pk_bf16_f32 %0, %1, %2" : "=v"(hi) : "v"(c2), "v"(c3));
    *(u32x2*)(op + dt * 16) = (u32x2){lo, hi};
  }
}

// ---------------------------------------------------------------------------
extern "C" void kernel_launch(void* const* d_in, const int* in_sizes, int n_in,
                              void* d_out, int out_size, void* d_ws, size_t ws_size,
                              hipStream_t stream) {
  const float* x = (const float*)d_in[0];
  const float* ln1g = (const float*)d_in[1];
  const float* ln1b = (const float*)d_in[2];
  const float* ln2g = (const float*)d_in[3];
  const float* ln2b = (const float*)d_in[4];
  const float* Wq = (const float*)d_in[5];
  const float* bq = (const float*)d_in[6];
  const float* Wk = (const float*)d_in[7];
  const float* bk = (const float*)d_in[8];
  const float* Wv = (const float*)d_in[9];
  const float* bv = (const float*)d_in[10];
  const float* Wo = (const float*)d_in[11];
  const float* bo = (const float*)d_in[12];
  const float* W1 = (const float*)d_in[13];
  const float* b1 = (const float*)d_in[14];
  const float* W2 = (const float*)d_in[15];
  const float* b2 = (const float*)d_in[16];

  char* ws = (char*)d_ws;
  u16* WqkvT = (u16*)(ws + 0);          //  3072*1024 bf16
  u16* WoT = (u16*)(ws + 6291456);      //  1024*1024 bf16
  u16* W1T = (u16*)(ws + 8388608);      //  4096*1024 bf16
  u16* W2T = (u16*)(ws + 16777216);     //  1024*4096 bf16
  u16* xn = (u16*)(ws + 25165824);      //  8192*1024 bf16
  float* x2 = (float*)(ws + 41943040);  //  8192*1024 f32
  u16* ctx = (u16*)(ws + 75497472);     //  8192*1024 bf16
  u16* big = (u16*)(ws + 92274688);     //  QKV then FFN h (union)
  u16* QKVb = big;
  u16* hbuf = big;
  float* outF = (float*)d_out;

  const dim3 tb(32, 8);
  transpose_cvt<<<dim3(32, 32), tb, 0, stream>>>(Wq, WqkvT, 1024, 1024);
  transpose_cvt<<<dim3(32, 32), tb, 0, stream>>>(Wk, WqkvT + 1024 * 1024, 1024, 1024);
  transpose_cvt<<<dim3(32, 32), tb, 0, stream>>>(Wv, WqkvT + 2048 * 1024, 1024, 1024);
  transpose_cvt<<<dim3(32, 32), tb, 0, stream>>>(Wo, WoT, 1024, 1024);
  transpose_cvt<<<dim3(128, 32), tb, 0, stream>>>(W1, W1T, 1024, 4096);
  transpose_cvt<<<dim3(32, 128), tb, 0, stream>>>(W2, W2T, 4096, 1024);

  // LN1
  ln_fwd<<<dim3(2048), dim3(256), 0, stream>>>(x, ln1g, ln1b, xn);
  // QKV fused GEMM (Q scaled by 0.125*log2e): M=8192 N=3072 K=1024
  gemm8p<8, 0><<<dim3(384), dim3(512), 0, stream>>>(xn, WqkvT, bq, bk, bv, nullptr,
                                                    (void*)QKVb, 8192, 3072, 1024, 12);
  // attention
  attn_fwd<<<dim3(32, 16, 4), dim3(256), 0, stream>>>(QKVb, ctx);
  // Wo + residual -> x2 (f32): M=8192 N=1024 K=1024 (BM=128 -> 256 wg)
  gemm8p<4, 2><<<dim3(256), dim3(512), 0, stream>>>(ctx, WoT, bo, nullptr, nullptr, x,
                                                    (void*)x2, 8192, 1024, 1024, 4);
  // LN2
  ln_fwd<<<dim3(2048), dim3(256), 0, stream>>>(x2, ln2g, ln2b, xn);
  // FFN1 (ReLU): M=8192 N=4096 K=1024
  gemm8p<8, 1><<<dim3(512), dim3(512), 0, stream>>>(xn, W1T, b1, nullptr, nullptr,
                                                    nullptr, (void*)hbuf, 8192, 4096, 1024, 16);
  // FFN2 + residual -> out (f32): M=8192 N=1024 K=4096 (BM=128 -> 256 wg)
  gemm8p<4, 2><<<dim3(256), dim3(512), 0, stream>>>(hbuf, W2T, b2, nullptr, nullptr, x2,
                                                    (void*)outF, 8192, 1024, 4096, 4);
}